// Round 1
// baseline (8022.320 us; speedup 1.0000x reference)
//
#include <hip/hip_runtime.h>
#include <math.h>

namespace {

constexpr int T_TOK = 16384;   // B*S
constexpr int D_DIM = 1024;
constexpr int E_EXP = 8;
constexpr int DFF_DIM = 4096;
constexpr int CAPN = 5120;     // capacity per expert

// fp32 vector GEMM tile config
constexpr int BM = 128, BN = 64, BK = 16;
constexpr int AS_LD = BM + 4;  // padded leading dim for transposed A tile

__device__ __forceinline__ float clip1000(float v) {
  return fminf(fmaxf(v, -1000.f), 1000.f);
}

// ---------------- Router: logits -> softmax -> top2 -> slot assignment ---------------
__global__ void router_kernel(const float* __restrict__ x,
                              const float* __restrict__ rw,
                              int* __restrict__ cnt,
                              int* __restrict__ toklist,
                              float* __restrict__ wlist) {
  const int t = blockIdx.x;
  const int lane = threadIdx.x;  // 64 lanes
  const float* xr = x + (size_t)t * D_DIM;
  float acc[E_EXP];
#pragma unroll
  for (int e = 0; e < E_EXP; ++e) acc[e] = 0.f;
  for (int d = lane; d < D_DIM; d += 64) {
    const float xv = xr[d];
    const float4 r0 = *(const float4*)(rw + (size_t)d * E_EXP);
    const float4 r1 = *(const float4*)(rw + (size_t)d * E_EXP + 4);
    acc[0] += xv * r0.x; acc[1] += xv * r0.y;
    acc[2] += xv * r0.z; acc[3] += xv * r0.w;
    acc[4] += xv * r1.x; acc[5] += xv * r1.y;
    acc[6] += xv * r1.z; acc[7] += xv * r1.w;
  }
#pragma unroll
  for (int e = 0; e < E_EXP; ++e) {
    float v = acc[e];
#pragma unroll
    for (int off = 32; off > 0; off >>= 1) v += __shfl_xor(v, off);
    acc[e] = v;
  }
  if (lane == 0) {
    float mx = -1e30f;
#pragma unroll
    for (int e = 0; e < E_EXP; ++e) {
      acc[e] = fminf(fmaxf(acc[e], -100.f), 100.f);  // clip logits like ref
      mx = fmaxf(mx, acc[e]);
    }
    float p[E_EXP];
    float s = 0.f;
#pragma unroll
    for (int e = 0; e < E_EXP; ++e) { p[e] = expf(acc[e] - mx); s += p[e]; }
    const float inv = 1.f / s;
    // top-2 with jax.lax.top_k tie rule (lower index wins): strict '>' replace
    int i1 = 0; float v1 = p[0];
#pragma unroll
    for (int e = 1; e < E_EXP; ++e) { if (p[e] > v1) { v1 = p[e]; i1 = e; } }
    int i2 = -1; float v2 = -1e30f;
#pragma unroll
    for (int e = 0; e < E_EXP; ++e) {
      if (e != i1 && p[e] > v2) { v2 = p[e]; i2 = e; }
    }
    v1 *= inv; v2 *= inv;
    const float wsum = fmaxf(v1 + v2, 1e-6f);
    const float w1 = v1 / wsum;
    const float w2 = v2 / wsum;
    const int s1 = atomicAdd(&cnt[i1], 1);
    if (s1 < CAPN) { toklist[i1 * CAPN + s1] = t; wlist[i1 * CAPN + s1] = w1; }
    const int s2 = atomicAdd(&cnt[i2], 1);
    if (s2 < CAPN) { toklist[i2 * CAPN + s2] = t; wlist[i2 * CAPN + s2] = w2; }
  }
}

// ---------------- Up-proj GEMM: h = clip(gelu(x[tok] @ w_up + b_up)) ---------------
// A: gathered x rows [CAPN x D_DIM] via toklist; B: w_up_e [D_DIM x DFF_DIM]
__global__ __launch_bounds__(256) void up_kernel(
    const float* __restrict__ x, const float* __restrict__ wup,
    const float* __restrict__ bup, const int* __restrict__ toklist,
    const int* __restrict__ cnt, float* __restrict__ h) {
  const int m0 = blockIdx.y * BM;
  const int rows_valid = min(*cnt, CAPN);
  if (m0 >= rows_valid) return;  // skip fully-padding tiles
  const int n0 = blockIdx.x * BN;
  __shared__ __align__(16) float As[BK][AS_LD];  // transposed: As[k][m]
  __shared__ __align__(16) float Bs[BK][BN];
  const int tid = threadIdx.x;
  // A staging: thread -> (row, 8 k's)
  const int r = tid >> 1;
  const int kq = (tid & 1) * 8;
  const float* arow = x + (size_t)toklist[m0 + r] * D_DIM + kq;
  // B staging: thread -> (k, 4 n's)
  const int bk = tid >> 4;
  const int bnn = (tid & 15) * 4;
  const float* bptr = wup + (size_t)bk * DFF_DIM + n0 + bnn;
  // micro tile: rows ty8..ty8+7, cols tx4..tx4+3
  const int ty8 = (tid >> 4) * 8;
  const int tx4 = (tid & 15) * 4;
  float acc[8][4];
#pragma unroll
  for (int i = 0; i < 8; ++i)
#pragma unroll
    for (int j = 0; j < 4; ++j) acc[i][j] = 0.f;

  for (int k0 = 0; k0 < D_DIM; k0 += BK) {
    const float4 a0 = *(const float4*)(arow + k0);
    const float4 a1 = *(const float4*)(arow + k0 + 4);
    const float4 b0 = *(const float4*)(bptr + (size_t)k0 * DFF_DIM);
    __syncthreads();  // previous iter's reads done before overwrite
    As[kq + 0][r] = a0.x; As[kq + 1][r] = a0.y;
    As[kq + 2][r] = a0.z; As[kq + 3][r] = a0.w;
    As[kq + 4][r] = a1.x; As[kq + 5][r] = a1.y;
    As[kq + 6][r] = a1.z; As[kq + 7][r] = a1.w;
    *(float4*)&Bs[bk][bnn] = b0;
    __syncthreads();
#pragma unroll
    for (int kk = 0; kk < BK; ++kk) {
      const float4 a0v = *(const float4*)&As[kk][ty8];
      const float4 a1v = *(const float4*)&As[kk][ty8 + 4];
      const float4 bv = *(const float4*)&Bs[kk][tx4];
      const float av[8] = {a0v.x, a0v.y, a0v.z, a0v.w,
                           a1v.x, a1v.y, a1v.z, a1v.w};
      const float bw[4] = {bv.x, bv.y, bv.z, bv.w};
#pragma unroll
      for (int i = 0; i < 8; ++i)
#pragma unroll
        for (int j = 0; j < 4; ++j) acc[i][j] += av[i] * bw[j];
    }
  }
  const float4 bb = *(const float4*)(bup + n0 + tx4);
  const float bias[4] = {bb.x, bb.y, bb.z, bb.w};
#pragma unroll
  for (int i = 0; i < 8; ++i) {
    float4 o;
    float* po = &o.x;
#pragma unroll
    for (int j = 0; j < 4; ++j) {
      float v = acc[i][j] + bias[j];
      v = 0.5f * v * (1.f + erff(v * 0.70710678118654752f));  // exact gelu
      po[j] = clip1000(v);
    }
    *(float4*)&h[(size_t)(m0 + ty8 + i) * DFF_DIM + n0 + tx4] = o;
  }
}

// ---------------- Down-proj GEMM: y[tok] += clip(h @ w_down + b_down) * w ----------
__global__ __launch_bounds__(256) void down_kernel(
    const float* __restrict__ h, const float* __restrict__ wdown,
    const float* __restrict__ bdown, const int* __restrict__ toklist,
    const float* __restrict__ wlist, const int* __restrict__ cnt,
    float* __restrict__ y) {
  const int m0 = blockIdx.y * BM;
  const int rows_valid = min(*cnt, CAPN);
  if (m0 >= rows_valid) return;
  const int n0 = blockIdx.x * BN;
  __shared__ __align__(16) float As[BK][AS_LD];
  __shared__ __align__(16) float Bs[BK][BN];
  const int tid = threadIdx.x;
  const int r = tid >> 1;
  const int kq = (tid & 1) * 8;
  const float* arow = h + (size_t)(m0 + r) * DFF_DIM + kq;
  const int bk = tid >> 4;
  const int bnn = (tid & 15) * 4;
  const float* bptr = wdown + (size_t)bk * D_DIM + n0 + bnn;
  const int ty8 = (tid >> 4) * 8;
  const int tx4 = (tid & 15) * 4;
  float acc[8][4];
#pragma unroll
  for (int i = 0; i < 8; ++i)
#pragma unroll
    for (int j = 0; j < 4; ++j) acc[i][j] = 0.f;

  for (int k0 = 0; k0 < DFF_DIM; k0 += BK) {
    const float4 a0 = *(const float4*)(arow + k0);
    const float4 a1 = *(const float4*)(arow + k0 + 4);
    const float4 b0 = *(const float4*)(bptr + (size_t)k0 * D_DIM);
    __syncthreads();
    As[kq + 0][r] = a0.x; As[kq + 1][r] = a0.y;
    As[kq + 2][r] = a0.z; As[kq + 3][r] = a0.w;
    As[kq + 4][r] = a1.x; As[kq + 5][r] = a1.y;
    As[kq + 6][r] = a1.z; As[kq + 7][r] = a1.w;
    *(float4*)&Bs[bk][bnn] = b0;
    __syncthreads();
#pragma unroll
    for (int kk = 0; kk < BK; ++kk) {
      const float4 a0v = *(const float4*)&As[kk][ty8];
      const float4 a1v = *(const float4*)&As[kk][ty8 + 4];
      const float4 bv = *(const float4*)&Bs[kk][tx4];
      const float av[8] = {a0v.x, a0v.y, a0v.z, a0v.w,
                           a1v.x, a1v.y, a1v.z, a1v.w};
      const float bw[4] = {bv.x, bv.y, bv.z, bv.w};
#pragma unroll
      for (int i = 0; i < 8; ++i)
#pragma unroll
        for (int j = 0; j < 4; ++j) acc[i][j] += av[i] * bw[j];
    }
  }
  const float4 bb = *(const float4*)(bdown + n0 + tx4);
  const float bias[4] = {bb.x, bb.y, bb.z, bb.w};
#pragma unroll
  for (int i = 0; i < 8; ++i) {
    const int m = m0 + ty8 + i;
    const float w = wlist[m];
    if (w != 0.f) {  // skip padding rows (avoids token-0 atomic contention)
      const int tok = toklist[m];
#pragma unroll
      for (int j = 0; j < 4; ++j) {
        const float v = clip1000(acc[i][j] + bias[j]) * w;
        atomicAdd(&y[(size_t)tok * D_DIM + n0 + tx4 + j], v);
      }
    }
  }
}

}  // namespace

extern "C" void kernel_launch(void* const* d_in, const int* in_sizes, int n_in,
                              void* d_out, int out_size, void* d_ws, size_t ws_size,
                              hipStream_t stream) {
  const float* x = (const float*)d_in[0];      // [B,S,D]
  const float* rw = (const float*)d_in[1];     // [D,E]
  const float* wup = (const float*)d_in[2];    // [E,D,DFF]
  const float* bup = (const float*)d_in[3];    // [E,DFF]
  const float* wdown = (const float*)d_in[4];  // [E,DFF,D]
  const float* bdown = (const float*)d_in[5];  // [E,D]
  float* y = (float*)d_out;

  // workspace layout (all offsets 256B-aligned):
  //   [0,32)                cnt[E]
  //   [256, +E*CAP*4)       toklist
  //   [.., +E*CAP*4)        wlist
  //   [327936, +CAP*DFF*4)  h buffer (reused across experts; ~80 MB)
  char* ws = (char*)d_ws;
  int* cnt = (int*)ws;
  int* toklist = (int*)(ws + 256);
  float* wlist = (float*)(ws + 256 + E_EXP * CAPN * 4);
  float* h = (float*)(ws + 256 + 2 * E_EXP * CAPN * 4);

  hipMemsetAsync(d_out, 0, (size_t)T_TOK * D_DIM * sizeof(float), stream);
  hipMemsetAsync(d_ws, 0, 256 + 2 * (size_t)E_EXP * CAPN * 4, stream);

  router_kernel<<<T_TOK, 64, 0, stream>>>(x, rw, cnt, toklist, wlist);

  for (int e = 0; e < E_EXP; ++e) {
    up_kernel<<<dim3(DFF_DIM / BN, CAPN / BM), 256, 0, stream>>>(
        x, wup + (size_t)e * D_DIM * DFF_DIM, bup + (size_t)e * DFF_DIM,
        toklist + e * CAPN, cnt + e, h);
    down_kernel<<<dim3(D_DIM / BN, CAPN / BM), 256, 0, stream>>>(
        h, wdown + (size_t)e * DFF_DIM * D_DIM, bdown + (size_t)e * D_DIM,
        toklist + e * CAPN, wlist + e * CAPN, cnt + e, y);
  }
}

// Round 2
// 3439.455 us; speedup vs baseline: 2.3324x; 2.3324x over previous
//
#include <hip/hip_runtime.h>
#include <math.h>

namespace {

constexpr int T_TOK = 16384;   // B*S
constexpr int D_DIM = 1024;
constexpr int E_EXP = 8;
constexpr int DFF_DIM = 4096;
constexpr int CAPN = 5120;     // capacity per expert

typedef __attribute__((ext_vector_type(8))) short bf16x8;
typedef __attribute__((ext_vector_type(16))) float f32x16;

__device__ __forceinline__ float clip1000(float v) {
  return fminf(fmaxf(v, -1000.f), 1000.f);
}
__device__ __forceinline__ unsigned short f2bf(float f) {
  unsigned u = __builtin_bit_cast(unsigned, f);
  u += 0x7FFFu + ((u >> 16) & 1u);           // RNE to bf16
  return (unsigned short)(u >> 16);
}
__device__ __forceinline__ float bf2f(unsigned short h) {
  return __builtin_bit_cast(float, (unsigned)h << 16);
}
__device__ __forceinline__ void gll16(const void* g, void* l) {
  __builtin_amdgcn_global_load_lds(
      (const __attribute__((address_space(1))) unsigned int*)g,
      (__attribute__((address_space(3))) unsigned int*)l, 16, 0, 0);
}

union Pack8 { unsigned short u[8]; uint4 v; };

// ---------------- Router: logits -> softmax -> top2 -> slot assignment ----------
__global__ void router_kernel(const float* __restrict__ x,
                              const float* __restrict__ rw,
                              int* __restrict__ cnt,
                              int* __restrict__ toklist,
                              float* __restrict__ wlist) {
  const int t = blockIdx.x;
  const int lane = threadIdx.x;  // 64 lanes
  const float* xr = x + (size_t)t * D_DIM;
  float acc[E_EXP];
#pragma unroll
  for (int e = 0; e < E_EXP; ++e) acc[e] = 0.f;
  for (int d = lane; d < D_DIM; d += 64) {
    const float xv = xr[d];
    const float4 r0 = *(const float4*)(rw + (size_t)d * E_EXP);
    const float4 r1 = *(const float4*)(rw + (size_t)d * E_EXP + 4);
    acc[0] += xv * r0.x; acc[1] += xv * r0.y;
    acc[2] += xv * r0.z; acc[3] += xv * r0.w;
    acc[4] += xv * r1.x; acc[5] += xv * r1.y;
    acc[6] += xv * r1.z; acc[7] += xv * r1.w;
  }
#pragma unroll
  for (int e = 0; e < E_EXP; ++e) {
    float v = acc[e];
#pragma unroll
    for (int off = 32; off > 0; off >>= 1) v += __shfl_xor(v, off);
    acc[e] = v;
  }
  if (lane == 0) {
    float mx = -1e30f;
#pragma unroll
    for (int e = 0; e < E_EXP; ++e) {
      acc[e] = fminf(fmaxf(acc[e], -100.f), 100.f);
      mx = fmaxf(mx, acc[e]);
    }
    float p[E_EXP];
    float s = 0.f;
#pragma unroll
    for (int e = 0; e < E_EXP; ++e) { p[e] = expf(acc[e] - mx); s += p[e]; }
    const float inv = 1.f / s;
    int i1 = 0; float v1 = p[0];
#pragma unroll
    for (int e = 1; e < E_EXP; ++e) { if (p[e] > v1) { v1 = p[e]; i1 = e; } }
    int i2 = -1; float v2 = -1e30f;
#pragma unroll
    for (int e = 0; e < E_EXP; ++e) {
      if (e != i1 && p[e] > v2) { v2 = p[e]; i2 = e; }
    }
    v1 *= inv; v2 *= inv;
    const float wsum = fmaxf(v1 + v2, 1e-6f);
    const float w1 = v1 / wsum;
    const float w2 = v2 / wsum;
    const int s1 = atomicAdd(&cnt[i1], 1);
    if (s1 < CAPN) { toklist[i1 * CAPN + s1] = t; wlist[i1 * CAPN + s1] = w1; }
    const int s2 = atomicAdd(&cnt[i2], 1);
    if (s2 < CAPN) { toklist[i2 * CAPN + s2] = t; wlist[i2 * CAPN + s2] = w2; }
  }
}

// ---------------- x -> (hi, lo) bf16 planes ----------------
__global__ __launch_bounds__(256) void xsplit_kernel(
    const float* __restrict__ x, unsigned short* __restrict__ xh,
    unsigned short* __restrict__ xl) {
  const size_t i = ((size_t)blockIdx.x * 256 + threadIdx.x) * 8;
  const float4 v0 = *(const float4*)(x + i);
  const float4 v1 = *(const float4*)(x + i + 4);
  const float vs[8] = {v0.x, v0.y, v0.z, v0.w, v1.x, v1.y, v1.z, v1.w};
  Pack8 ph, pl;
#pragma unroll
  for (int j = 0; j < 8; ++j) {
    const unsigned short hi = f2bf(vs[j]);
    ph.u[j] = hi;
    pl.u[j] = f2bf(vs[j] - bf2f(hi));
  }
  *(uint4*)(xh + i) = ph.v;
  *(uint4*)(xl + i) = pl.v;
}

// ------------- weight [K][N] fp32 -> grouped [K/8][N][8] bf16 hi/lo -------------
__global__ __launch_bounds__(256) void wconv_kernel(
    const float* __restrict__ src, unsigned short* __restrict__ dhi,
    unsigned short* __restrict__ dlo, int logN) {
  const int tid = blockIdx.x * 256 + threadIdx.x;
  const int N = 1 << logN;
  const int g = tid >> logN;
  const int n = tid & (N - 1);
  const float* s = src + (size_t)(g * 8) * N + n;
  Pack8 ph, pl;
#pragma unroll
  for (int j = 0; j < 8; ++j) {
    const float v = s[(size_t)j * N];
    const unsigned short hi = f2bf(v);
    ph.u[j] = hi;
    pl.u[j] = f2bf(v - bf2f(hi));
  }
  const size_t o = ((size_t)g * N + n) * 8;
  *(uint4*)(dhi + o) = ph.v;
  *(uint4*)(dlo + o) = pl.v;
}

#define MFMA4(A_, B_)                                                              \
  acc[0][0] = __builtin_amdgcn_mfma_f32_32x32x16_bf16(A_[0], B_[0], acc[0][0], 0, 0, 0); \
  acc[0][1] = __builtin_amdgcn_mfma_f32_32x32x16_bf16(A_[0], B_[1], acc[0][1], 0, 0, 0); \
  acc[1][0] = __builtin_amdgcn_mfma_f32_32x32x16_bf16(A_[1], B_[0], acc[1][0], 0, 0, 0); \
  acc[1][1] = __builtin_amdgcn_mfma_f32_32x32x16_bf16(A_[1], B_[1], acc[1][1], 0, 0, 0);

union UpLds {
  unsigned short stage[16][128][8];  // planes: A_hi[0..3] A_lo[4..7] B_hi[8..11] B_lo[12..15]
  unsigned short ctile[128][132];    // padded bf16 C tile for transposed writeout
};

// -------- Up GEMM: h = clip(gelu(gather(x)[128xK] @ w_up + b)) -> split-bf16 ------
__global__ __launch_bounds__(256) void up_mfma(
    const unsigned short* __restrict__ xh, const unsigned short* __restrict__ xl,
    const unsigned short* __restrict__ wbh, const unsigned short* __restrict__ wbl,
    const float* __restrict__ bup, const int* __restrict__ toklist,
    const int* __restrict__ cnt, unsigned short* __restrict__ hhi,
    unsigned short* __restrict__ hlo) {
  const int valid = min(*cnt, CAPN);
  const int m0 = blockIdx.y * 128;
  if (m0 >= valid) return;
  const int n0 = blockIdx.x * 128;
  __shared__ __align__(16) UpLds lds;
  const int tid = threadIdx.x;
  const int l = tid & 63, w = tid >> 6;
  const int t0 = toklist[m0 + l];
  const int t1 = toklist[m0 + 64 + l];
  const size_t a0 = (size_t)t0 * D_DIM + w * 8;   // element offsets
  const size_t a1 = (size_t)t1 * D_DIM + w * 8;
  const int mb = (w >> 1) * 64, nb = (w & 1) * 64;
  const int r = l & 31, kg = l >> 5;
  f32x16 acc[2][2];
#pragma unroll
  for (int i = 0; i < 2; ++i)
#pragma unroll
    for (int j = 0; j < 2; ++j) acc[i][j] = 0.f;

#pragma unroll 1
  for (int k0 = 0; k0 < D_DIM; k0 += 32) {
    __syncthreads();
    const size_t gG = (size_t)(k0 >> 3) + w;
    gll16(xh + a0 + k0, &lds.stage[w][0][0]);
    gll16(xh + a1 + k0, &lds.stage[w][64][0]);
    gll16(xl + a0 + k0, &lds.stage[4 + w][0][0]);
    gll16(xl + a1 + k0, &lds.stage[4 + w][64][0]);
    const unsigned short* bsh = wbh + (gG * DFF_DIM + n0 + l) * 8;
    const unsigned short* bsl = wbl + (gG * DFF_DIM + n0 + l) * 8;
    gll16(bsh, &lds.stage[8 + w][0][0]);
    gll16(bsh + 64 * 8, &lds.stage[8 + w][64][0]);
    gll16(bsl, &lds.stage[12 + w][0][0]);
    gll16(bsl + 64 * 8, &lds.stage[12 + w][64][0]);
    __syncthreads();
#pragma unroll
    for (int ks = 0; ks < 2; ++ks) {
      const int pk = ks * 2 + kg;
      bf16x8 a_h[2], a_l[2], b_h[2], b_l[2];
#pragma unroll
      for (int mf = 0; mf < 2; ++mf) {
        a_h[mf] = *(const bf16x8*)&lds.stage[pk][mb + mf * 32 + r][0];
        a_l[mf] = *(const bf16x8*)&lds.stage[4 + pk][mb + mf * 32 + r][0];
      }
#pragma unroll
      for (int nf = 0; nf < 2; ++nf) {
        b_h[nf] = *(const bf16x8*)&lds.stage[8 + pk][nb + nf * 32 + r][0];
        b_l[nf] = *(const bf16x8*)&lds.stage[12 + pk][nb + nf * 32 + r][0];
      }
      MFMA4(a_h, b_h)
      MFMA4(a_h, b_l)
      MFMA4(a_l, b_h)
    }
  }
  // ---- epilogue: bias + gelu + clip, split to hi/lo, write grouped layout ----
  __syncthreads();
  const int col = l & 31;
  const float bias0 = bup[n0 + nb + col];
  const float bias1 = bup[n0 + nb + 32 + col];
#pragma unroll
  for (int mf = 0; mf < 2; ++mf)
#pragma unroll
    for (int nf = 0; nf < 2; ++nf) {
      const float bias = nf ? bias1 : bias0;
#pragma unroll
      for (int rg = 0; rg < 16; ++rg) {
        float v = acc[mf][nf][rg] + bias;
        v = 0.5f * v * (1.f + erff(v * 0.70710678118654752f));
        v = clip1000(v);
        const unsigned short hi = f2bf(v);
        const int row = (rg & 3) + 8 * (rg >> 2) + 4 * kg;
        lds.ctile[mb + mf * 32 + row][nb + nf * 32 + col] = hi;
        acc[mf][nf][rg] = v - bf2f(hi);  // residual for lo pass
      }
    }
  __syncthreads();
#pragma unroll
  for (int it = 0; it < 8; ++it) {
    const int chunk = it * 256 + tid;
    const int gg = chunk >> 7, m = chunk & 127;
    const unsigned short* cr = &lds.ctile[m][gg * 8];
    const uint2 q0 = *(const uint2*)cr;
    const uint2 q1 = *(const uint2*)(cr + 4);
    *(uint4*)&hhi[((size_t)((n0 >> 3) + gg) * CAPN + (m0 + m)) * 8] =
        make_uint4(q0.x, q0.y, q1.x, q1.y);
  }
  __syncthreads();
#pragma unroll
  for (int mf = 0; mf < 2; ++mf)
#pragma unroll
    for (int nf = 0; nf < 2; ++nf)
#pragma unroll
      for (int rg = 0; rg < 16; ++rg) {
        const int row = (rg & 3) + 8 * (rg >> 2) + 4 * kg;
        lds.ctile[mb + mf * 32 + row][nb + nf * 32 + col] = f2bf(acc[mf][nf][rg]);
      }
  __syncthreads();
#pragma unroll
  for (int it = 0; it < 8; ++it) {
    const int chunk = it * 256 + tid;
    const int gg = chunk >> 7, m = chunk & 127;
    const unsigned short* cr = &lds.ctile[m][gg * 8];
    const uint2 q0 = *(const uint2*)cr;
    const uint2 q1 = *(const uint2*)(cr + 4);
    *(uint4*)&hlo[((size_t)((n0 >> 3) + gg) * CAPN + (m0 + m)) * 8] =
        make_uint4(q0.x, q0.y, q1.x, q1.y);
  }
}

// -------- Down GEMM (split-K=4): partial[kc] = h @ w_down (raw fp32 sums) --------
__global__ __launch_bounds__(256) void down_mfma(
    const unsigned short* __restrict__ hhi, const unsigned short* __restrict__ hlo,
    const unsigned short* __restrict__ wbh, const unsigned short* __restrict__ wbl,
    const int* __restrict__ cnt, float* __restrict__ partial) {
  const int valid = min(*cnt, CAPN);
  const int m0 = blockIdx.y * 128;
  if (m0 >= valid) return;
  const int n0 = blockIdx.x * 128;
  const int kc = blockIdx.z;
  __shared__ __align__(16) unsigned short stage[16][128][8];
  const int tid = threadIdx.x;
  const int l = tid & 63, w = tid >> 6;
  const int mb = (w >> 1) * 64, nb = (w & 1) * 64;
  const int r = l & 31, kg = l >> 5;
  f32x16 acc[2][2];
#pragma unroll
  for (int i = 0; i < 2; ++i)
#pragma unroll
    for (int j = 0; j < 2; ++j) acc[i][j] = 0.f;

  const int kbeg = kc * 1024;
#pragma unroll 1
  for (int k0 = kbeg; k0 < kbeg + 1024; k0 += 32) {
    __syncthreads();
    const size_t gG = (size_t)(k0 >> 3) + w;
    const unsigned short* ash = hhi + (gG * CAPN + m0 + l) * 8;
    const unsigned short* asl = hlo + (gG * CAPN + m0 + l) * 8;
    gll16(ash, &stage[w][0][0]);
    gll16(ash + 64 * 8, &stage[w][64][0]);
    gll16(asl, &stage[4 + w][0][0]);
    gll16(asl + 64 * 8, &stage[4 + w][64][0]);
    const unsigned short* bsh = wbh + (gG * D_DIM + n0 + l) * 8;
    const unsigned short* bsl = wbl + (gG * D_DIM + n0 + l) * 8;
    gll16(bsh, &stage[8 + w][0][0]);
    gll16(bsh + 64 * 8, &stage[8 + w][64][0]);
    gll16(bsl, &stage[12 + w][0][0]);
    gll16(bsl + 64 * 8, &stage[12 + w][64][0]);
    __syncthreads();
#pragma unroll
    for (int ks = 0; ks < 2; ++ks) {
      const int pk = ks * 2 + kg;
      bf16x8 a_h[2], a_l[2], b_h[2], b_l[2];
#pragma unroll
      for (int mf = 0; mf < 2; ++mf) {
        a_h[mf] = *(const bf16x8*)&stage[pk][mb + mf * 32 + r][0];
        a_l[mf] = *(const bf16x8*)&stage[4 + pk][mb + mf * 32 + r][0];
      }
#pragma unroll
      for (int nf = 0; nf < 2; ++nf) {
        b_h[nf] = *(const bf16x8*)&stage[8 + pk][nb + nf * 32 + r][0];
        b_l[nf] = *(const bf16x8*)&stage[12 + pk][nb + nf * 32 + r][0];
      }
      MFMA4(a_h, b_h)
      MFMA4(a_h, b_l)
      MFMA4(a_l, b_h)
    }
  }
  const int col = l & 31;
#pragma unroll
  for (int mf = 0; mf < 2; ++mf)
#pragma unroll
    for (int nf = 0; nf < 2; ++nf)
#pragma unroll
      for (int rg = 0; rg < 16; ++rg) {
        const int row = (rg & 3) + 8 * (rg >> 2) + 4 * kg;
        const int m = m0 + mb + mf * 32 + row;
        const int n = n0 + nb + nf * 32 + col;
        partial[((size_t)kc * CAPN + m) * D_DIM + n] = acc[mf][nf][rg];
      }
}

// -------- finalize: sum split-K, bias+clip, *weight, atomic scatter into y --------
__global__ __launch_bounds__(256) void finalize_kernel(
    const float* __restrict__ partial, const float* __restrict__ bdown,
    const int* __restrict__ toklist, const float* __restrict__ wlist,
    const int* __restrict__ cnt, float* __restrict__ y) {
  const int idx = blockIdx.x * 256 + threadIdx.x;
  const int m = idx >> 8;
  const int nq = (idx & 255) * 4;
  const int valid = min(*cnt, CAPN);
  if (m >= valid) return;
  const float w = wlist[m];
  if (w == 0.f) return;
  constexpr size_t PS = (size_t)CAPN * D_DIM;
  const float* p = partial + (size_t)m * D_DIM + nq;
  const float4 s0 = *(const float4*)p;
  const float4 s1 = *(const float4*)(p + PS);
  const float4 s2 = *(const float4*)(p + 2 * PS);
  const float4 s3 = *(const float4*)(p + 3 * PS);
  const float4 bb = *(const float4*)(bdown + nq);
  const int tok = toklist[m];
  float* yp = y + (size_t)tok * D_DIM + nq;
  atomicAdd(yp + 0, clip1000(s0.x + s1.x + s2.x + s3.x + bb.x) * w);
  atomicAdd(yp + 1, clip1000(s0.y + s1.y + s2.y + s3.y + bb.y) * w);
  atomicAdd(yp + 2, clip1000(s0.z + s1.z + s2.z + s3.z + bb.z) * w);
  atomicAdd(yp + 3, clip1000(s0.w + s1.w + s2.w + s3.w + bb.w) * w);
}

// ================= fp32 fallback (round-0 kernels, used only if ws too small) ====
constexpr int BM = 128, BN = 64, BK = 16;
constexpr int AS_LD = BM + 4;

__global__ __launch_bounds__(256) void up_f32(
    const float* __restrict__ x, const float* __restrict__ wup,
    const float* __restrict__ bup, const int* __restrict__ toklist,
    const int* __restrict__ cnt, float* __restrict__ h) {
  const int m0 = blockIdx.y * BM;
  const int rows_valid = min(*cnt, CAPN);
  if (m0 >= rows_valid) return;
  const int n0 = blockIdx.x * BN;
  __shared__ __align__(16) float As[BK][AS_LD];
  __shared__ __align__(16) float Bs[BK][BN];
  const int tid = threadIdx.x;
  const int r = tid >> 1;
  const int kq = (tid & 1) * 8;
  const float* arow = x + (size_t)toklist[m0 + r] * D_DIM + kq;
  const int bk = tid >> 4;
  const int bnn = (tid & 15) * 4;
  const float* bptr = wup + (size_t)bk * DFF_DIM + n0 + bnn;
  const int ty8 = (tid >> 4) * 8;
  const int tx4 = (tid & 15) * 4;
  float acc[8][4];
#pragma unroll
  for (int i = 0; i < 8; ++i)
#pragma unroll
    for (int j = 0; j < 4; ++j) acc[i][j] = 0.f;
  for (int k0 = 0; k0 < D_DIM; k0 += BK) {
    const float4 a0 = *(const float4*)(arow + k0);
    const float4 a1 = *(const float4*)(arow + k0 + 4);
    const float4 b0 = *(const float4*)(bptr + (size_t)k0 * DFF_DIM);
    __syncthreads();
    As[kq + 0][r] = a0.x; As[kq + 1][r] = a0.y;
    As[kq + 2][r] = a0.z; As[kq + 3][r] = a0.w;
    As[kq + 4][r] = a1.x; As[kq + 5][r] = a1.y;
    As[kq + 6][r] = a1.z; As[kq + 7][r] = a1.w;
    *(float4*)&Bs[bk][bnn] = b0;
    __syncthreads();
#pragma unroll
    for (int kk = 0; kk < BK; ++kk) {
      const float4 a0v = *(const float4*)&As[kk][ty8];
      const float4 a1v = *(const float4*)&As[kk][ty8 + 4];
      const float4 bv = *(const float4*)&Bs[kk][tx4];
      const float av[8] = {a0v.x, a0v.y, a0v.z, a0v.w, a1v.x, a1v.y, a1v.z, a1v.w};
      const float bw[4] = {bv.x, bv.y, bv.z, bv.w};
#pragma unroll
      for (int i = 0; i < 8; ++i)
#pragma unroll
        for (int j = 0; j < 4; ++j) acc[i][j] += av[i] * bw[j];
    }
  }
  const float4 bb = *(const float4*)(bup + n0 + tx4);
  const float bias[4] = {bb.x, bb.y, bb.z, bb.w};
#pragma unroll
  for (int i = 0; i < 8; ++i) {
    float4 o;
    float* po = &o.x;
#pragma unroll
    for (int j = 0; j < 4; ++j) {
      float v = acc[i][j] + bias[j];
      v = 0.5f * v * (1.f + erff(v * 0.70710678118654752f));
      po[j] = clip1000(v);
    }
    *(float4*)&h[(size_t)(m0 + ty8 + i) * DFF_DIM + n0 + tx4] = o;
  }
}

__global__ __launch_bounds__(256) void down_f32(
    const float* __restrict__ h, const float* __restrict__ wdown,
    const float* __restrict__ bdown, const int* __restrict__ toklist,
    const float* __restrict__ wlist, const int* __restrict__ cnt,
    float* __restrict__ y) {
  const int m0 = blockIdx.y * BM;
  const int rows_valid = min(*cnt, CAPN);
  if (m0 >= rows_valid) return;
  const int n0 = blockIdx.x * BN;
  __shared__ __align__(16) float As[BK][AS_LD];
  __shared__ __align__(16) float Bs[BK][BN];
  const int tid = threadIdx.x;
  const int r = tid >> 1;
  const int kq = (tid & 1) * 8;
  const float* arow = h + (size_t)(m0 + r) * DFF_DIM + kq;
  const int bk = tid >> 4;
  const int bnn = (tid & 15) * 4;
  const float* bptr = wdown + (size_t)bk * D_DIM + n0 + bnn;
  const int ty8 = (tid >> 4) * 8;
  const int tx4 = (tid & 15) * 4;
  float acc[8][4];
#pragma unroll
  for (int i = 0; i < 8; ++i)
#pragma unroll
    for (int j = 0; j < 4; ++j) acc[i][j] = 0.f;
  for (int k0 = 0; k0 < DFF_DIM; k0 += BK) {
    const float4 a0 = *(const float4*)(arow + k0);
    const float4 a1 = *(const float4*)(arow + k0 + 4);
    const float4 b0 = *(const float4*)(bptr + (size_t)k0 * D_DIM);
    __syncthreads();
    As[kq + 0][r] = a0.x; As[kq + 1][r] = a0.y;
    As[kq + 2][r] = a0.z; As[kq + 3][r] = a0.w;
    As[kq + 4][r] = a1.x; As[kq + 5][r] = a1.y;
    As[kq + 6][r] = a1.z; As[kq + 7][r] = a1.w;
    *(float4*)&Bs[bk][bnn] = b0;
    __syncthreads();
#pragma unroll
    for (int kk = 0; kk < BK; ++kk) {
      const float4 a0v = *(const float4*)&As[kk][ty8];
      const float4 a1v = *(const float4*)&As[kk][ty8 + 4];
      const float4 bv = *(const float4*)&Bs[kk][tx4];
      const float av[8] = {a0v.x, a0v.y, a0v.z, a0v.w, a1v.x, a1v.y, a1v.z, a1v.w};
      const float bw[4] = {bv.x, bv.y, bv.z, bv.w};
#pragma unroll
      for (int i = 0; i < 8; ++i)
#pragma unroll
        for (int j = 0; j < 4; ++j) acc[i][j] += av[i] * bw[j];
    }
  }
  const float4 bb = *(const float4*)(bdown + n0 + tx4);
  const float bias[4] = {bb.x, bb.y, bb.z, bb.w};
#pragma unroll
  for (int i = 0; i < 8; ++i) {
    const int m = m0 + ty8 + i;
    const float w = wlist[m];
    if (w != 0.f) {
      const int tok = toklist[m];
#pragma unroll
      for (int j = 0; j < 4; ++j) {
        const float v = clip1000(acc[i][j] + bias[j]) * w;
        atomicAdd(&y[(size_t)tok * D_DIM + n0 + tx4 + j], v);
      }
    }
  }
}

}  // namespace

extern "C" void kernel_launch(void* const* d_in, const int* in_sizes, int n_in,
                              void* d_out, int out_size, void* d_ws, size_t ws_size,
                              hipStream_t stream) {
  const float* x = (const float*)d_in[0];
  const float* rw = (const float*)d_in[1];
  const float* wup = (const float*)d_in[2];
  const float* bup = (const float*)d_in[3];
  const float* wdown = (const float*)d_in[4];
  const float* bdown = (const float*)d_in[5];
  float* y = (float*)d_out;
  char* ws = (char*)d_ws;

  int* cnt = (int*)ws;
  int* toklist = (int*)(ws + 256);
  float* wlist = (float*)(ws + 256 + E_EXP * CAPN * 4);

  // ---- MFMA-path workspace layout ----
  constexpr size_t OFF_XH = 393216;
  constexpr size_t SZ_X = (size_t)T_TOK * D_DIM * 2;          // 32 MiB
  constexpr size_t OFF_XL = OFF_XH + SZ_X;
  constexpr size_t SZ_H = (size_t)CAPN * DFF_DIM * 2;         // 40 MiB (one plane)
  constexpr size_t OFF_HHI = OFF_XL + SZ_X;
  constexpr size_t OFF_HLO = OFF_HHI + SZ_H;
  constexpr size_t SZ_PART = 4ull * CAPN * D_DIM * 4;         // 80 MiB
  constexpr size_t OFF_PART = OFF_HLO + SZ_H;
  constexpr size_t OFF_WB = OFF_PART + SZ_PART;
  constexpr size_t SZ_WPLANE = (size_t)D_DIM * DFF_DIM * 2;   // 8 MiB per plane
  constexpr size_t SZ_WEXP = 4 * SZ_WPLANE;                   // up hi/lo + down hi/lo
  constexpr size_t NEED_ONE = OFF_WB + SZ_WEXP;
  constexpr size_t NEED_ALL = OFF_WB + 8 * SZ_WEXP;

  hipMemsetAsync(d_out, 0, (size_t)T_TOK * D_DIM * sizeof(float), stream);
  hipMemsetAsync(d_ws, 0, 393216, stream);
  router_kernel<<<T_TOK, 64, 0, stream>>>(x, rw, cnt, toklist, wlist);

  if (ws_size >= NEED_ONE) {
    unsigned short* xh = (unsigned short*)(ws + OFF_XH);
    unsigned short* xl = (unsigned short*)(ws + OFF_XL);
    unsigned short* hhi = (unsigned short*)(ws + OFF_HHI);
    unsigned short* hlo = (unsigned short*)(ws + OFF_HLO);
    float* partial = (float*)(ws + OFF_PART);
    const bool all = ws_size >= NEED_ALL;
    const size_t wstride = all ? SZ_WEXP : 0;

    xsplit_kernel<<<(T_TOK * D_DIM) / (256 * 8), 256, 0, stream>>>(x, xh, xl);

    if (all) {
      for (int e = 0; e < E_EXP; ++e) {
        char* wb = ws + OFF_WB + e * SZ_WEXP;
        wconv_kernel<<<2048, 256, 0, stream>>>(
            wup + (size_t)e * D_DIM * DFF_DIM, (unsigned short*)wb,
            (unsigned short*)(wb + SZ_WPLANE), 12);
        wconv_kernel<<<2048, 256, 0, stream>>>(
            wdown + (size_t)e * DFF_DIM * D_DIM,
            (unsigned short*)(wb + 2 * SZ_WPLANE),
            (unsigned short*)(wb + 3 * SZ_WPLANE), 10);
      }
    }
    for (int e = 0; e < E_EXP; ++e) {
      char* wb = ws + OFF_WB + e * wstride;
      unsigned short* wubh = (unsigned short*)wb;
      unsigned short* wubl = (unsigned short*)(wb + SZ_WPLANE);
      unsigned short* wdbh = (unsigned short*)(wb + 2 * SZ_WPLANE);
      unsigned short* wdbl = (unsigned short*)(wb + 3 * SZ_WPLANE);
      if (!all) {
        wconv_kernel<<<2048, 256, 0, stream>>>(
            wup + (size_t)e * D_DIM * DFF_DIM, wubh, wubl, 12);
        wconv_kernel<<<2048, 256, 0, stream>>>(
            wdown + (size_t)e * DFF_DIM * D_DIM, wdbh, wdbl, 10);
      }
      up_mfma<<<dim3(DFF_DIM / 128, CAPN / 128), 256, 0, stream>>>(
          xh, xl, wubh, wubl, bup + (size_t)e * DFF_DIM, toklist + e * CAPN,
          cnt + e, hhi, hlo);
      down_mfma<<<dim3(D_DIM / 128, CAPN / 128, 4), 256, 0, stream>>>(
          hhi, hlo, wdbh, wdbl, cnt + e, partial);
      finalize_kernel<<<(CAPN * D_DIM / 4) / 256, 256, 0, stream>>>(
          partial, bdown + (size_t)e * D_DIM, toklist + e * CAPN,
          wlist + e * CAPN, cnt + e, y);
    }
  } else {
    // fp32 fallback (round-0 path)
    float* h = (float*)(ws + 256 + 2 * E_EXP * CAPN * 4);
    for (int e = 0; e < E_EXP; ++e) {
      up_f32<<<dim3(DFF_DIM / BN, CAPN / BM), 256, 0, stream>>>(
          x, wup + (size_t)e * D_DIM * DFF_DIM, bup + (size_t)e * DFF_DIM,
          toklist + e * CAPN, cnt + e, h);
      down_f32<<<dim3(D_DIM / BN, CAPN / BM), 256, 0, stream>>>(
          h, wdown + (size_t)e * DFF_DIM * D_DIM, bdown + (size_t)e * D_DIM,
          toklist + e * CAPN, wlist + e * CAPN, cnt + e, y);
    }
  }
}

// Round 3
// 3063.810 us; speedup vs baseline: 2.6184x; 1.1226x over previous
//
#include <hip/hip_runtime.h>
#include <math.h>

namespace {

constexpr int T_TOK = 16384;   // B*S
constexpr int D_DIM = 1024;
constexpr int E_EXP = 8;
constexpr int DFF_DIM = 4096;
constexpr int CAPN = 5120;     // capacity per expert

typedef __attribute__((ext_vector_type(8))) short bf16x8;
typedef __attribute__((ext_vector_type(16))) float f32x16;

__device__ __forceinline__ float clip1000(float v) {
  return fminf(fmaxf(v, -1000.f), 1000.f);
}
__device__ __forceinline__ unsigned short f2bf(float f) {
  unsigned u = __builtin_bit_cast(unsigned, f);
  u += 0x7FFFu + ((u >> 16) & 1u);           // RNE to bf16
  return (unsigned short)(u >> 16);
}
__device__ __forceinline__ float bf2f(unsigned short h) {
  return __builtin_bit_cast(float, (unsigned)h << 16);
}
__device__ __forceinline__ void gll16(const void* g, void* l) {
  __builtin_amdgcn_global_load_lds(
      (const __attribute__((address_space(1))) unsigned int*)g,
      (__attribute__((address_space(3))) unsigned int*)l, 16, 0, 0);
}

union Pack8 { unsigned short u[8]; uint4 v; };

// ---------------- Router phase A: logits -> softmax -> top2 (no atomics) --------
__global__ __launch_bounds__(256) void router_score(
    const float* __restrict__ x, const float* __restrict__ rw,
    int* __restrict__ topi, float2* __restrict__ topw) {
  const int t = blockIdx.x * 4 + (threadIdx.x >> 6);
  const int lane = threadIdx.x & 63;
  const float* xr = x + (size_t)t * D_DIM;
  float acc[E_EXP];
#pragma unroll
  for (int e = 0; e < E_EXP; ++e) acc[e] = 0.f;
  for (int d = lane; d < D_DIM; d += 64) {
    const float xv = xr[d];
    const float4 r0 = *(const float4*)(rw + (size_t)d * E_EXP);
    const float4 r1 = *(const float4*)(rw + (size_t)d * E_EXP + 4);
    acc[0] += xv * r0.x; acc[1] += xv * r0.y;
    acc[2] += xv * r0.z; acc[3] += xv * r0.w;
    acc[4] += xv * r1.x; acc[5] += xv * r1.y;
    acc[6] += xv * r1.z; acc[7] += xv * r1.w;
  }
#pragma unroll
  for (int e = 0; e < E_EXP; ++e) {
    float v = acc[e];
#pragma unroll
    for (int off = 32; off > 0; off >>= 1) v += __shfl_xor(v, off);
    acc[e] = v;
  }
  if (lane == 0) {
    float mx = -1e30f;
#pragma unroll
    for (int e = 0; e < E_EXP; ++e) {
      acc[e] = fminf(fmaxf(acc[e], -100.f), 100.f);  // ref clips logits
      mx = fmaxf(mx, acc[e]);
    }
    float p[E_EXP];
    float s = 0.f;
#pragma unroll
    for (int e = 0; e < E_EXP; ++e) { p[e] = expf(acc[e] - mx); s += p[e]; }
    const float inv = 1.f / s;
    // top-2, jax.lax.top_k tie rule (lower index wins): strict '>' replace
    int i1 = 0; float v1 = p[0];
#pragma unroll
    for (int e = 1; e < E_EXP; ++e) { if (p[e] > v1) { v1 = p[e]; i1 = e; } }
    int i2 = -1; float v2 = -1e30f;
#pragma unroll
    for (int e = 0; e < E_EXP; ++e) {
      if (e != i1 && p[e] > v2) { v2 = p[e]; i2 = e; }
    }
    v1 *= inv; v2 *= inv;
    const float wsum = fmaxf(v1 + v2, 1e-6f);
    topi[t] = i1 | (i2 << 8);
    topw[t] = make_float2(v1 / wsum, v2 / wsum);
  }
}

// ------- Router phase B: LDS-aggregated slot assignment (512 global atomics) -----
__global__ __launch_bounds__(256) void router_assign(
    const int* __restrict__ topi, const float2* __restrict__ topw,
    int* __restrict__ cnt, int* __restrict__ toklist,
    float* __restrict__ wlist) {
  __shared__ int lcnt[E_EXP];
  __shared__ int lbase[E_EXP];
  const int tid = threadIdx.x;
  const int t = blockIdx.x * 256 + tid;
  if (tid < E_EXP) lcnt[tid] = 0;
  __syncthreads();
  const int pk = topi[t];
  const float2 w = topw[t];
  const int e1 = pk & 0xff, e2 = pk >> 8;
  atomicAdd(&lcnt[e1], 1);
  atomicAdd(&lcnt[e2], 1);
  __syncthreads();
  if (tid < E_EXP) {
    lbase[tid] = atomicAdd(&cnt[tid], lcnt[tid]);  // one global atomic per expert
    lcnt[tid] = 0;
  }
  __syncthreads();
  const int s1 = lbase[e1] + atomicAdd(&lcnt[e1], 1);
  if (s1 < CAPN) { toklist[e1 * CAPN + s1] = t; wlist[e1 * CAPN + s1] = w.x; }
  const int s2 = lbase[e2] + atomicAdd(&lcnt[e2], 1);
  if (s2 < CAPN) { toklist[e2 * CAPN + s2] = t; wlist[e2 * CAPN + s2] = w.y; }
}

// ---------------- x -> (hi, lo) bf16 planes ----------------
__global__ __launch_bounds__(256) void xsplit_kernel(
    const float* __restrict__ x, unsigned short* __restrict__ xh,
    unsigned short* __restrict__ xl) {
  const size_t i = ((size_t)blockIdx.x * 256 + threadIdx.x) * 8;
  const float4 v0 = *(const float4*)(x + i);
  const float4 v1 = *(const float4*)(x + i + 4);
  const float vs[8] = {v0.x, v0.y, v0.z, v0.w, v1.x, v1.y, v1.z, v1.w};
  Pack8 ph, pl;
#pragma unroll
  for (int j = 0; j < 8; ++j) {
    const unsigned short hi = f2bf(vs[j]);
    ph.u[j] = hi;
    pl.u[j] = f2bf(vs[j] - bf2f(hi));
  }
  *(uint4*)(xh + i) = ph.v;
  *(uint4*)(xl + i) = pl.v;
}

// ------ weight [E][K][N] fp32 -> grouped [K/8][N][8] bf16 hi/lo (per expert) -----
__global__ __launch_bounds__(256) void wconv_kernel(
    const float* __restrict__ src, unsigned short* __restrict__ dhi,
    unsigned short* __restrict__ dlo, int logN, size_t src_estride,
    size_t dst_estride) {
  const int tid = blockIdx.x * 256 + threadIdx.x;
  const int e = blockIdx.y;
  const int N = 1 << logN;
  const int g = tid >> logN;
  const int n = tid & (N - 1);
  const float* s = src + e * src_estride + (size_t)(g * 8) * N + n;
  Pack8 ph, pl;
#pragma unroll
  for (int j = 0; j < 8; ++j) {
    const float v = s[(size_t)j * N];
    const unsigned short hi = f2bf(v);
    ph.u[j] = hi;
    pl.u[j] = f2bf(v - bf2f(hi));
  }
  const size_t o = dst_estride * e + ((size_t)g * N + n) * 8;
  *(uint4*)(dhi + o) = ph.v;
  *(uint4*)(dlo + o) = pl.v;
}

#define MFMA4(A_, B_)                                                              \
  acc[0][0] = __builtin_amdgcn_mfma_f32_32x32x16_bf16(A_[0], B_[0], acc[0][0], 0, 0, 0); \
  acc[0][1] = __builtin_amdgcn_mfma_f32_32x32x16_bf16(A_[0], B_[1], acc[0][1], 0, 0, 0); \
  acc[1][0] = __builtin_amdgcn_mfma_f32_32x32x16_bf16(A_[1], B_[0], acc[1][0], 0, 0, 0); \
  acc[1][1] = __builtin_amdgcn_mfma_f32_32x32x16_bf16(A_[1], B_[1], acc[1][1], 0, 0, 0);

union UpLds {
  unsigned short stage[16][128][8];  // planes: A_hi[0..3] A_lo[4..7] B_hi[8..11] B_lo[12..15]
  unsigned short ctile[128][132];    // padded bf16 C tile for transposed writeout
};

// -------- Up GEMM: h = clip(gelu(gather(x)[128xK] @ w_up + b)) -> split-bf16 ------
__global__ __launch_bounds__(256) void up_mfma(
    const unsigned short* __restrict__ xh, const unsigned short* __restrict__ xl,
    const unsigned short* __restrict__ wbh, const unsigned short* __restrict__ wbl,
    const float* __restrict__ bup, const int* __restrict__ toklist,
    const int* __restrict__ cnt, unsigned short* __restrict__ hhi,
    unsigned short* __restrict__ hlo) {
  const int valid = min(*cnt, CAPN);
  const int m0 = blockIdx.y * 128;
  if (m0 >= valid) return;
  const int n0 = blockIdx.x * 128;
  __shared__ __align__(16) UpLds lds;
  const int tid = threadIdx.x;
  const int l = tid & 63, w = tid >> 6;
  const int t0 = toklist[m0 + l];
  const int t1 = toklist[m0 + 64 + l];
  const size_t a0 = (size_t)t0 * D_DIM + w * 8;   // element offsets
  const size_t a1 = (size_t)t1 * D_DIM + w * 8;
  const int mb = (w >> 1) * 64, nb = (w & 1) * 64;
  const int r = l & 31, kg = l >> 5;
  f32x16 acc[2][2];
#pragma unroll
  for (int i = 0; i < 2; ++i)
#pragma unroll
    for (int j = 0; j < 2; ++j) acc[i][j] = 0.f;

#pragma unroll 1
  for (int k0 = 0; k0 < D_DIM; k0 += 32) {
    __syncthreads();
    const size_t gG = (size_t)(k0 >> 3) + w;
    gll16(xh + a0 + k0, &lds.stage[w][0][0]);
    gll16(xh + a1 + k0, &lds.stage[w][64][0]);
    gll16(xl + a0 + k0, &lds.stage[4 + w][0][0]);
    gll16(xl + a1 + k0, &lds.stage[4 + w][64][0]);
    const unsigned short* bsh = wbh + (gG * DFF_DIM + n0 + l) * 8;
    const unsigned short* bsl = wbl + (gG * DFF_DIM + n0 + l) * 8;
    gll16(bsh, &lds.stage[8 + w][0][0]);
    gll16(bsh + 64 * 8, &lds.stage[8 + w][64][0]);
    gll16(bsl, &lds.stage[12 + w][0][0]);
    gll16(bsl + 64 * 8, &lds.stage[12 + w][64][0]);
    __syncthreads();
#pragma unroll
    for (int ks = 0; ks < 2; ++ks) {
      const int pk = ks * 2 + kg;
      bf16x8 a_h[2], a_l[2], b_h[2], b_l[2];
#pragma unroll
      for (int mf = 0; mf < 2; ++mf) {
        a_h[mf] = *(const bf16x8*)&lds.stage[pk][mb + mf * 32 + r][0];
        a_l[mf] = *(const bf16x8*)&lds.stage[4 + pk][mb + mf * 32 + r][0];
      }
#pragma unroll
      for (int nf = 0; nf < 2; ++nf) {
        b_h[nf] = *(const bf16x8*)&lds.stage[8 + pk][nb + nf * 32 + r][0];
        b_l[nf] = *(const bf16x8*)&lds.stage[12 + pk][nb + nf * 32 + r][0];
      }
      MFMA4(a_h, b_h)
      MFMA4(a_h, b_l)
      MFMA4(a_l, b_h)
    }
  }
  // ---- epilogue: bias + gelu + clip, split to hi/lo, write grouped layout ----
  __syncthreads();
  const int col = l & 31;
  const float bias0 = bup[n0 + nb + col];
  const float bias1 = bup[n0 + nb + 32 + col];
#pragma unroll
  for (int mf = 0; mf < 2; ++mf)
#pragma unroll
    for (int nf = 0; nf < 2; ++nf) {
      const float bias = nf ? bias1 : bias0;
#pragma unroll
      for (int rg = 0; rg < 16; ++rg) {
        float v = acc[mf][nf][rg] + bias;
        v = 0.5f * v * (1.f + erff(v * 0.70710678118654752f));
        v = clip1000(v);
        const unsigned short hi = f2bf(v);
        const int row = (rg & 3) + 8 * (rg >> 2) + 4 * kg;
        lds.ctile[mb + mf * 32 + row][nb + nf * 32 + col] = hi;
        acc[mf][nf][rg] = v - bf2f(hi);  // residual for lo pass
      }
    }
  __syncthreads();
#pragma unroll
  for (int it = 0; it < 8; ++it) {
    const int chunk = it * 256 + tid;
    const int gg = chunk >> 7, m = chunk & 127;
    const unsigned short* cr = &lds.ctile[m][gg * 8];
    const uint2 q0 = *(const uint2*)cr;
    const uint2 q1 = *(const uint2*)(cr + 4);
    *(uint4*)&hhi[((size_t)((n0 >> 3) + gg) * CAPN + (m0 + m)) * 8] =
        make_uint4(q0.x, q0.y, q1.x, q1.y);
  }
  __syncthreads();
#pragma unroll
  for (int mf = 0; mf < 2; ++mf)
#pragma unroll
    for (int nf = 0; nf < 2; ++nf)
#pragma unroll
      for (int rg = 0; rg < 16; ++rg) {
        const int row = (rg & 3) + 8 * (rg >> 2) + 4 * kg;
        lds.ctile[mb + mf * 32 + row][nb + nf * 32 + col] = f2bf(acc[mf][nf][rg]);
      }
  __syncthreads();
#pragma unroll
  for (int it = 0; it < 8; ++it) {
    const int chunk = it * 256 + tid;
    const int gg = chunk >> 7, m = chunk & 127;
    const unsigned short* cr = &lds.ctile[m][gg * 8];
    const uint2 q0 = *(const uint2*)cr;
    const uint2 q1 = *(const uint2*)(cr + 4);
    *(uint4*)&hlo[((size_t)((n0 >> 3) + gg) * CAPN + (m0 + m)) * 8] =
        make_uint4(q0.x, q0.y, q1.x, q1.y);
  }
}

// -------- Down GEMM (split-K=4): partial[kc] = h @ w_down (raw fp32 sums) --------
__global__ __launch_bounds__(256) void down_mfma(
    const unsigned short* __restrict__ hhi, const unsigned short* __restrict__ hlo,
    const unsigned short* __restrict__ wbh, const unsigned short* __restrict__ wbl,
    const int* __restrict__ cnt, float* __restrict__ partial) {
  const int valid = min(*cnt, CAPN);
  const int m0 = blockIdx.y * 128;
  if (m0 >= valid) return;
  const int n0 = blockIdx.x * 128;
  const int kc = blockIdx.z;
  __shared__ __align__(16) unsigned short stage[16][128][8];
  const int tid = threadIdx.x;
  const int l = tid & 63, w = tid >> 6;
  const int mb = (w >> 1) * 64, nb = (w & 1) * 64;
  const int r = l & 31, kg = l >> 5;
  f32x16 acc[2][2];
#pragma unroll
  for (int i = 0; i < 2; ++i)
#pragma unroll
    for (int j = 0; j < 2; ++j) acc[i][j] = 0.f;

  const int kbeg = kc * 1024;
#pragma unroll 1
  for (int k0 = kbeg; k0 < kbeg + 1024; k0 += 32) {
    __syncthreads();
    const size_t gG = (size_t)(k0 >> 3) + w;
    const unsigned short* ash = hhi + (gG * CAPN + m0 + l) * 8;
    const unsigned short* asl = hlo + (gG * CAPN + m0 + l) * 8;
    gll16(ash, &stage[w][0][0]);
    gll16(ash + 64 * 8, &stage[w][64][0]);
    gll16(asl, &stage[4 + w][0][0]);
    gll16(asl + 64 * 8, &stage[4 + w][64][0]);
    const unsigned short* bsh = wbh + (gG * D_DIM + n0 + l) * 8;
    const unsigned short* bsl = wbl + (gG * D_DIM + n0 + l) * 8;
    gll16(bsh, &stage[8 + w][0][0]);
    gll16(bsh + 64 * 8, &stage[8 + w][64][0]);
    gll16(bsl, &stage[12 + w][0][0]);
    gll16(bsl + 64 * 8, &stage[12 + w][64][0]);
    __syncthreads();
#pragma unroll
    for (int ks = 0; ks < 2; ++ks) {
      const int pk = ks * 2 + kg;
      bf16x8 a_h[2], a_l[2], b_h[2], b_l[2];
#pragma unroll
      for (int mf = 0; mf < 2; ++mf) {
        a_h[mf] = *(const bf16x8*)&stage[pk][mb + mf * 32 + r][0];
        a_l[mf] = *(const bf16x8*)&stage[4 + pk][mb + mf * 32 + r][0];
      }
#pragma unroll
      for (int nf = 0; nf < 2; ++nf) {
        b_h[nf] = *(const bf16x8*)&stage[8 + pk][nb + nf * 32 + r][0];
        b_l[nf] = *(const bf16x8*)&stage[12 + pk][nb + nf * 32 + r][0];
      }
      MFMA4(a_h, b_h)
      MFMA4(a_h, b_l)
      MFMA4(a_l, b_h)
    }
  }
  const int col = l & 31;
#pragma unroll
  for (int mf = 0; mf < 2; ++mf)
#pragma unroll
    for (int nf = 0; nf < 2; ++nf)
#pragma unroll
      for (int rg = 0; rg < 16; ++rg) {
        const int row = (rg & 3) + 8 * (rg >> 2) + 4 * kg;
        const int m = m0 + mb + mf * 32 + row;
        const int n = n0 + nb + nf * 32 + col;
        partial[((size_t)kc * CAPN + m) * D_DIM + n] = acc[mf][nf][rg];
      }
}

// -------- finalize: sum split-K, bias+clip, *weight, atomic scatter into y --------
__global__ __launch_bounds__(256) void finalize_kernel(
    const float* __restrict__ partial, const float* __restrict__ bdown,
    const int* __restrict__ toklist, const float* __restrict__ wlist,
    const int* __restrict__ cnt, float* __restrict__ y) {
  const int idx = blockIdx.x * 256 + threadIdx.x;
  const int m = idx >> 8;
  const int nq = (idx & 255) * 4;
  const int valid = min(*cnt, CAPN);
  if (m >= valid) return;
  const float w = wlist[m];
  if (w == 0.f) return;
  constexpr size_t PS = (size_t)CAPN * D_DIM;
  const float* p = partial + (size_t)m * D_DIM + nq;
  const float4 s0 = *(const float4*)p;
  const float4 s1 = *(const float4*)(p + PS);
  const float4 s2 = *(const float4*)(p + 2 * PS);
  const float4 s3 = *(const float4*)(p + 3 * PS);
  const float4 bb = *(const float4*)(bdown + nq);
  const int tok = toklist[m];
  float* yp = y + (size_t)tok * D_DIM + nq;
  atomicAdd(yp + 0, clip1000(s0.x + s1.x + s2.x + s3.x + bb.x) * w);
  atomicAdd(yp + 1, clip1000(s0.y + s1.y + s2.y + s3.y + bb.y) * w);
  atomicAdd(yp + 2, clip1000(s0.z + s1.z + s2.z + s3.z + bb.z) * w);
  atomicAdd(yp + 3, clip1000(s0.w + s1.w + s2.w + s3.w + bb.w) * w);
}

// ================= fp32 fallback (used only if ws too small) ====
constexpr int BM = 128, BN = 64, BK = 16;
constexpr int AS_LD = BM + 4;

__global__ __launch_bounds__(256) void up_f32(
    const float* __restrict__ x, const float* __restrict__ wup,
    const float* __restrict__ bup, const int* __restrict__ toklist,
    const int* __restrict__ cnt, float* __restrict__ h) {
  const int m0 = blockIdx.y * BM;
  const int rows_valid = min(*cnt, CAPN);
  if (m0 >= rows_valid) return;
  const int n0 = blockIdx.x * BN;
  __shared__ __align__(16) float As[BK][AS_LD];
  __shared__ __align__(16) float Bs[BK][BN];
  const int tid = threadIdx.x;
  const int r = tid >> 1;
  const int kq = (tid & 1) * 8;
  const float* arow = x + (size_t)toklist[m0 + r] * D_DIM + kq;
  const int bk = tid >> 4;
  const int bnn = (tid & 15) * 4;
  const float* bptr = wup + (size_t)bk * DFF_DIM + n0 + bnn;
  const int ty8 = (tid >> 4) * 8;
  const int tx4 = (tid & 15) * 4;
  float acc[8][4];
#pragma unroll
  for (int i = 0; i < 8; ++i)
#pragma unroll
    for (int j = 0; j < 4; ++j) acc[i][j] = 0.f;
  for (int k0 = 0; k0 < D_DIM; k0 += BK) {
    const float4 a0 = *(const float4*)(arow + k0);
    const float4 a1 = *(const float4*)(arow + k0 + 4);
    const float4 b0 = *(const float4*)(bptr + (size_t)k0 * DFF_DIM);
    __syncthreads();
    As[kq + 0][r] = a0.x; As[kq + 1][r] = a0.y;
    As[kq + 2][r] = a0.z; As[kq + 3][r] = a0.w;
    As[kq + 4][r] = a1.x; As[kq + 5][r] = a1.y;
    As[kq + 6][r] = a1.z; As[kq + 7][r] = a1.w;
    *(float4*)&Bs[bk][bnn] = b0;
    __syncthreads();
#pragma unroll
    for (int kk = 0; kk < BK; ++kk) {
      const float4 a0v = *(const float4*)&As[kk][ty8];
      const float4 a1v = *(const float4*)&As[kk][ty8 + 4];
      const float4 bv = *(const float4*)&Bs[kk][tx4];
      const float av[8] = {a0v.x, a0v.y, a0v.z, a0v.w, a1v.x, a1v.y, a1v.z, a1v.w};
      const float bw[4] = {bv.x, bv.y, bv.z, bv.w};
#pragma unroll
      for (int i = 0; i < 8; ++i)
#pragma unroll
        for (int j = 0; j < 4; ++j) acc[i][j] += av[i] * bw[j];
    }
  }
  const float4 bb = *(const float4*)(bup + n0 + tx4);
  const float bias[4] = {bb.x, bb.y, bb.z, bb.w};
#pragma unroll
  for (int i = 0; i < 8; ++i) {
    float4 o;
    float* po = &o.x;
#pragma unroll
    for (int j = 0; j < 4; ++j) {
      float v = acc[i][j] + bias[j];
      v = 0.5f * v * (1.f + erff(v * 0.70710678118654752f));
      po[j] = clip1000(v);
    }
    *(float4*)&h[(size_t)(m0 + ty8 + i) * DFF_DIM + n0 + tx4] = o;
  }
}

__global__ __launch_bounds__(256) void down_f32(
    const float* __restrict__ h, const float* __restrict__ wdown,
    const float* __restrict__ bdown, const int* __restrict__ toklist,
    const float* __restrict__ wlist, const int* __restrict__ cnt,
    float* __restrict__ y) {
  const int m0 = blockIdx.y * BM;
  const int rows_valid = min(*cnt, CAPN);
  if (m0 >= rows_valid) return;
  const int n0 = blockIdx.x * BN;
  __shared__ __align__(16) float As[BK][AS_LD];
  __shared__ __align__(16) float Bs[BK][BN];
  const int tid = threadIdx.x;
  const int r = tid >> 1;
  const int kq = (tid & 1) * 8;
  const float* arow = h + (size_t)(m0 + r) * DFF_DIM + kq;
  const int bk = tid >> 4;
  const int bnn = (tid & 15) * 4;
  const float* bptr = wdown + (size_t)bk * D_DIM + n0 + bnn;
  const int ty8 = (tid >> 4) * 8;
  const int tx4 = (tid & 15) * 4;
  float acc[8][4];
#pragma unroll
  for (int i = 0; i < 8; ++i)
#pragma unroll
    for (int j = 0; j < 4; ++j) acc[i][j] = 0.f;
  for (int k0 = 0; k0 < DFF_DIM; k0 += BK) {
    const float4 a0 = *(const float4*)(arow + k0);
    const float4 a1 = *(const float4*)(arow + k0 + 4);
    const float4 b0 = *(const float4*)(bptr + (size_t)k0 * D_DIM);
    __syncthreads();
    As[kq + 0][r] = a0.x; As[kq + 1][r] = a0.y;
    As[kq + 2][r] = a0.z; As[kq + 3][r] = a0.w;
    As[kq + 4][r] = a1.x; As[kq + 5][r] = a1.y;
    As[kq + 6][r] = a1.z; As[kq + 7][r] = a1.w;
    *(float4*)&Bs[bk][bnn] = b0;
    __syncthreads();
#pragma unroll
    for (int kk = 0; kk < BK; ++kk) {
      const float4 a0v = *(const float4*)&As[kk][ty8];
      const float4 a1v = *(const float4*)&As[kk][ty8 + 4];
      const float4 bv = *(const float4*)&Bs[kk][tx4];
      const float av[8] = {a0v.x, a0v.y, a0v.z, a0v.w, a1v.x, a1v.y, a1v.z, a1v.w};
      const float bw[4] = {bv.x, bv.y, bv.z, bv.w};
#pragma unroll
      for (int i = 0; i < 8; ++i)
#pragma unroll
        for (int j = 0; j < 4; ++j) acc[i][j] += av[i] * bw[j];
    }
  }
  const float4 bb = *(const float4*)(bdown + n0 + tx4);
  const float bias[4] = {bb.x, bb.y, bb.z, bb.w};
#pragma unroll
  for (int i = 0; i < 8; ++i) {
    const int m = m0 + ty8 + i;
    const float w = wlist[m];
    if (w != 0.f) {
      const int tok = toklist[m];
#pragma unroll
      for (int j = 0; j < 4; ++j) {
        const float v = clip1000(acc[i][j] + bias[j]) * w;
        atomicAdd(&y[(size_t)tok * D_DIM + n0 + tx4 + j], v);
      }
    }
  }
}

}  // namespace

extern "C" void kernel_launch(void* const* d_in, const int* in_sizes, int n_in,
                              void* d_out, int out_size, void* d_ws, size_t ws_size,
                              hipStream_t stream) {
  const float* x = (const float*)d_in[0];
  const float* rw = (const float*)d_in[1];
  const float* wup = (const float*)d_in[2];
  const float* bup = (const float*)d_in[3];
  const float* wdown = (const float*)d_in[4];
  const float* bdown = (const float*)d_in[5];
  float* y = (float*)d_out;
  char* ws = (char*)d_ws;

  // ---- routing metadata layout ----
  constexpr size_t OFF_TOK = 1024;                       // E*CAP ints  (160 KB)
  constexpr size_t OFF_WL = OFF_TOK + (size_t)E_EXP * CAPN * 4;
  constexpr size_t OFF_TOPI = OFF_WL + (size_t)E_EXP * CAPN * 4;   // T ints
  constexpr size_t OFF_TOPW = OFF_TOPI + (size_t)T_TOK * 4;        // T float2
  constexpr size_t OFF_XH = OFF_TOPW + (size_t)T_TOK * 8;          // ~525 KB

  int* cnt = (int*)ws;
  int* toklist = (int*)(ws + OFF_TOK);
  float* wlist = (float*)(ws + OFF_WL);
  int* topi = (int*)(ws + OFF_TOPI);
  float2* topw = (float2*)(ws + OFF_TOPW);

  // ---- MFMA-path workspace layout ----
  constexpr size_t SZ_X = (size_t)T_TOK * D_DIM * 2;          // 32 MiB
  constexpr size_t OFF_XL = OFF_XH + SZ_X;
  constexpr size_t SZ_H = (size_t)CAPN * DFF_DIM * 2;         // 40 MiB (one plane)
  constexpr size_t OFF_HHI = OFF_XL + SZ_X;
  constexpr size_t OFF_HLO = OFF_HHI + SZ_H;
  constexpr size_t SZ_PART = 4ull * CAPN * D_DIM * 4;         // 80 MiB
  constexpr size_t OFF_PART = OFF_HLO + SZ_H;
  constexpr size_t OFF_WB = OFF_PART + SZ_PART;
  constexpr size_t SZ_WPLANE = (size_t)D_DIM * DFF_DIM * 2;   // 8 MiB per plane
  constexpr size_t SZ_WEXP = 4 * SZ_WPLANE;                   // up hi/lo + down hi/lo
  constexpr size_t NEED_ONE = OFF_WB + SZ_WEXP;
  constexpr size_t NEED_ALL = OFF_WB + 8 * SZ_WEXP;

  hipMemsetAsync(d_out, 0, (size_t)T_TOK * D_DIM * sizeof(float), stream);
  hipMemsetAsync(d_ws, 0, OFF_TOPI, stream);  // cnt + toklist + wlist

  router_score<<<T_TOK / 4, 256, 0, stream>>>(x, rw, topi, topw);
  router_assign<<<T_TOK / 256, 256, 0, stream>>>(topi, topw, cnt, toklist, wlist);

  if (ws_size >= NEED_ONE) {
    unsigned short* xh = (unsigned short*)(ws + OFF_XH);
    unsigned short* xl = (unsigned short*)(ws + OFF_XL);
    unsigned short* hhi = (unsigned short*)(ws + OFF_HHI);
    unsigned short* hlo = (unsigned short*)(ws + OFF_HLO);
    float* partial = (float*)(ws + OFF_PART);
    const bool all = ws_size >= NEED_ALL;
    const size_t wstride = all ? SZ_WEXP : 0;

    xsplit_kernel<<<(T_TOK * D_DIM) / (256 * 8), 256, 0, stream>>>(x, xh, xl);

    if (all) {
      char* wb = ws + OFF_WB;
      wconv_kernel<<<dim3(2048, 8), 256, 0, stream>>>(
          wup, (unsigned short*)wb, (unsigned short*)(wb + SZ_WPLANE), 12,
          (size_t)D_DIM * DFF_DIM, SZ_WEXP / 2);
      wconv_kernel<<<dim3(2048, 8), 256, 0, stream>>>(
          wdown, (unsigned short*)(wb + 2 * SZ_WPLANE),
          (unsigned short*)(wb + 3 * SZ_WPLANE), 10,
          (size_t)DFF_DIM * D_DIM, SZ_WEXP / 2);
    }
    for (int e = 0; e < E_EXP; ++e) {
      char* wb = ws + OFF_WB + e * wstride;
      unsigned short* wubh = (unsigned short*)wb;
      unsigned short* wubl = (unsigned short*)(wb + SZ_WPLANE);
      unsigned short* wdbh = (unsigned short*)(wb + 2 * SZ_WPLANE);
      unsigned short* wdbl = (unsigned short*)(wb + 3 * SZ_WPLANE);
      if (!all) {
        wconv_kernel<<<dim3(2048, 1), 256, 0, stream>>>(
            wup + (size_t)e * D_DIM * DFF_DIM, wubh, wubl, 12, 0, 0);
        wconv_kernel<<<dim3(2048, 1), 256, 0, stream>>>(
            wdown + (size_t)e * DFF_DIM * D_DIM, wdbh, wdbl, 10, 0, 0);
      }
      up_mfma<<<dim3(DFF_DIM / 128, CAPN / 128), 256, 0, stream>>>(
          xh, xl, wubh, wubl, bup + (size_t)e * DFF_DIM, toklist + e * CAPN,
          cnt + e, hhi, hlo);
      down_mfma<<<dim3(D_DIM / 128, CAPN / 128, 4), 256, 0, stream>>>(
          hhi, hlo, wdbh, wdbl, cnt + e, partial);
      finalize_kernel<<<(CAPN * D_DIM / 4) / 256, 256, 0, stream>>>(
          partial, bdown + (size_t)e * D_DIM, toklist + e * CAPN,
          wlist + e * CAPN, cnt + e, y);
    }
  } else {
    // fp32 fallback
    float* h = (float*)(ws + OFF_XH);
    for (int e = 0; e < E_EXP; ++e) {
      up_f32<<<dim3(DFF_DIM / BN, CAPN / BM), 256, 0, stream>>>(
          x, wup + (size_t)e * D_DIM * DFF_DIM, bup + (size_t)e * DFF_DIM,
          toklist + e * CAPN, cnt + e, h);
      down_f32<<<dim3(D_DIM / BN, CAPN / BM), 256, 0, stream>>>(
          h, wdown + (size_t)e * DFF_DIM * D_DIM, bdown + (size_t)e * D_DIM,
          toklist + e * CAPN, wlist + e * CAPN, cnt + e, y);
    }
  }
}